// Round 8
// baseline (3547.169 us; speedup 1.0000x reference)
//
#include <hip/hip_runtime.h>
#include <math.h>

// GraphWaveNet forward — Round 8: round-7 structure + bf16 dot2 (v_dot2_f32_bf16)
// in accum/gate + skip fused into gate (k_skip removed; last layer launches
// gate only at t=Tn-1).
//
// Z = xg @ [S_a|S_b|S_c] (N=6144), k_accum mixes (32x32 per group, dot2) into
// bf16 nxt; pass 1 adds resid+BN. nxt pre-init by k_gate (gcn bias + W0*xg).
// ST slice order [S0,S0^2,S1,S1^2,S2,S2^2]^T; pass p slices 3p..3p+2,
// W cols 32+96p+32g. skip telescopes: gate blocks at t==Tn-1 also compute the
// 256-ch skip projection from in-register activations. End head = MFMA.
//
// Workspace (BL=16 if ws >= 239,075,328 B else BL=8):
//   ST    6 x 2048^2 bf16                      @0           50,331,648
//   skip  16x256x2048 f32                      @50,331,648  33,554,432
//   bufA  BL x 32 x 13 x 2048 bf16             @83,886,080  BL*1,703,936
//   bufB  same                                 (adjacent)
//   xg    BL x 32 x 12 x 2048 bf16             (adjacent)   BL*1,572,864
//   Z     (BL*32*12) x 6144 bf16               (adjacent)   BL*4,718,592
// Overlays: adp f32 @Z, Sbf bf16 @bufA (startup); h bf16 @bufA.., skipT
// @bufA+33.5MB, E1bf @ST (post-loop; skip f32 region untouched).

#define NNODE 2048
#define NLAYER 8
#define SSTR ((size_t)NNODE * NNODE)

typedef unsigned short u16;
typedef unsigned int u32;
typedef __attribute__((ext_vector_type(8))) short bf16x8;
typedef __attribute__((ext_vector_type(4))) float f32x4;

__device__ __forceinline__ u16 f2bf(float f) {
    unsigned u = __builtin_bit_cast(unsigned, f);
    u += 0x7fffu + ((u >> 16) & 1u);   // round-to-nearest-even
    return (u16)(u >> 16);
}
__device__ __forceinline__ float bf2f(u16 h) {
    unsigned u = ((unsigned)h) << 16;
    return __builtin_bit_cast(float, u);
}
__device__ __forceinline__ float bflo(u32 p) { return __builtin_bit_cast(float, p << 16); }
__device__ __forceinline__ float bfhi(u32 p) { return __builtin_bit_cast(float, p & 0xffff0000u); }
__device__ __forceinline__ u32 pack2(float a, float b) {
    return (u32)f2bf(a) | ((u32)f2bf(b) << 16);
}

// dot2: acc += w.lo*x.lo + w.hi*x.hi  (pairs of bf16, f32 accumulate)
#if defined(__has_builtin) && __has_builtin(__builtin_amdgcn_fdot2_f32_bf16)
typedef __attribute__((ext_vector_type(2))) __bf16 bf2v;
__device__ __forceinline__ float dot2bf(u32 w, u32 x, float acc) {
    return __builtin_amdgcn_fdot2_f32_bf16(__builtin_bit_cast(bf2v, w),
                                           __builtin_bit_cast(bf2v, x), acc, false);
}
#else
__device__ __forceinline__ float dot2bf(u32 w, u32 x, float acc) {
    return acc + bflo(w) * bflo(x) + bfhi(w) * bfhi(x);
}
#endif

__device__ __forceinline__ void gld16(const void* g, void* l) {
    __builtin_amdgcn_global_load_lds(
        (const __attribute__((address_space(1))) unsigned int*)g,
        (__attribute__((address_space(3))) unsigned int*)l, 16, 0, 0);
}

// ---------------- adp = softmax(relu(nv1 @ nv2), axis=1) ----------------
__global__ __launch_bounds__(256) void k_adp_mm(const float* __restrict__ nv1,
                                                const float* __restrict__ nv2,
                                                float* __restrict__ P) {
    int v = blockIdx.y;
    int w = blockIdx.x * 256 + threadIdx.x;
    float acc = 0.f;
#pragma unroll
    for (int k = 0; k < 10; ++k) acc += nv1[v * 10 + k] * nv2[k * NNODE + w];
    P[(size_t)v * NNODE + w] = acc;
}

__global__ __launch_bounds__(256) void k_softmax(float* __restrict__ P) {
    int v = blockIdx.x, tid = threadIdx.x;
    float* row = P + (size_t)v * NNODE;
    float m = 0.f;
    for (int w = tid; w < NNODE; w += 256) m = fmaxf(m, fmaxf(row[w], 0.f));
#pragma unroll
    for (int off = 32; off > 0; off >>= 1) m = fmaxf(m, __shfl_down(m, off));
    __shared__ float redm[4];
    __shared__ float reds[4];
    int wave = tid >> 6, lane = tid & 63;
    if (lane == 0) redm[wave] = m;
    __syncthreads();
    m = fmaxf(fmaxf(redm[0], redm[1]), fmaxf(redm[2], redm[3]));
    float s = 0.f;
    for (int w = tid; w < NNODE; w += 256) s += expf(fmaxf(row[w], 0.f) - m);
#pragma unroll
    for (int off = 32; off > 0; off >>= 1) s += __shfl_down(s, off);
    if (lane == 0) reds[wave] = s;
    __syncthreads();
    s = reds[0] + reds[1] + reds[2] + reds[3];
    float inv = 1.f / s;
    for (int w = tid; w < NNODE; w += 256) row[w] = expf(fmaxf(row[w], 0.f) - m) * inv;
}

// ---- supports: S_s^T bf16 -> ST slice 2s; straight-cast S bf16 -> Sbf ----
__global__ __launch_bounds__(256) void k_transp(const float* __restrict__ A,
                                                const float* __restrict__ adp,
                                                u16* __restrict__ ST,
                                                u16* __restrict__ Sbf) {
    __shared__ float tile[32][33];
    int s = blockIdx.z;
    const float* src = (s < 2) ? (A + (size_t)s * SSTR) : adp;
    int v0 = blockIdx.y * 32, w0 = blockIdx.x * 32;
    int tx = threadIdx.x & 31, ty = threadIdx.x >> 5;  // 32 x 8
    u16* dst2 = Sbf + (size_t)s * SSTR;
#pragma unroll
    for (int p = 0; p < 4; ++p) {
        float v = src[(size_t)(v0 + ty + p * 8) * NNODE + w0 + tx];
        tile[ty + p * 8][tx] = v;
        dst2[(size_t)(v0 + ty + p * 8) * NNODE + w0 + tx] = f2bf(v);
    }
    __syncthreads();
    u16* dst = ST + (size_t)(2 * s) * SSTR;
#pragma unroll
    for (int p = 0; p < 4; ++p)
        dst[(size_t)(w0 + ty + p * 8) * NNODE + v0 + tx] = f2bf(tile[tx][ty + p * 8]);
}

// ---- generic bf16 MFMA GEMM (startup S^2 only): C[m,n]=sum_k A[m,k]*BT[n,k] ----
__global__ __launch_bounds__(256) void k_gemm_mfma(
    const u16* __restrict__ A, int lda, size_t asstr,
    const u16* __restrict__ BT, size_t bsstr,
    u16* __restrict__ C, int ldc, size_t csstr, int sbase) {
    __shared__ u16 Asl[128 * 32];
    __shared__ u16 Bsl[128 * 32];
    const int tid = threadIdx.x;
    const int wave = tid >> 6, lane = tid & 63;
    const int sidx = sbase + blockIdx.z;
    const u16* Ab = A + sidx * asstr + (size_t)blockIdx.y * 128 * lda;
    const u16* Bb = BT + sidx * bsstr + (size_t)blockIdx.x * 128 * NNODE;
    const int tr = tid >> 2;
    const int tc = (tid & 3) * 8;
    char* AslB = (char*)Asl + wave * 1024;
    char* BslB = (char*)Bsl + wave * 1024;
    const int wm = (wave & 1) * 64, wn = (wave >> 1) * 64;
    const int fr = lane & 15;
    const int fk = (lane >> 4) * 8;
    f32x4 acc[4][4];
#pragma unroll
    for (int i = 0; i < 4; ++i)
#pragma unroll
        for (int j = 0; j < 4; ++j) acc[i][j] = (f32x4){0.f, 0.f, 0.f, 0.f};

    for (int k0 = 0; k0 < 2048; k0 += 32) {
        gld16(Ab + (size_t)tr * lda + k0 + tc, AslB);
        gld16(Ab + (size_t)(tr + 64) * lda + k0 + tc, AslB + 4096);
        gld16(Bb + (size_t)tr * NNODE + k0 + tc, BslB);
        gld16(Bb + (size_t)(tr + 64) * NNODE + k0 + tc, BslB + 4096);
        __syncthreads();
        bf16x8 af[4], bf[4];
#pragma unroll
        for (int i = 0; i < 4; ++i)
            af[i] = *(const bf16x8*)&Asl[(wm + i * 16 + fr) * 32 + fk];
#pragma unroll
        for (int j = 0; j < 4; ++j)
            bf[j] = *(const bf16x8*)&Bsl[(wn + j * 16 + fr) * 32 + fk];
#pragma unroll
        for (int i = 0; i < 4; ++i)
#pragma unroll
            for (int j = 0; j < 4; ++j)
                acc[i][j] = __builtin_amdgcn_mfma_f32_16x16x32_bf16(af[i], bf[j], acc[i][j], 0, 0, 0);
        __syncthreads();
    }
    u16* Cb = C + sidx * csstr + (size_t)(blockIdx.y * 128 + wm) * ldc + blockIdx.x * 128 + wn;
    const int orow = (lane >> 4) * 4;
#pragma unroll
    for (int i = 0; i < 4; ++i)
#pragma unroll
        for (int j = 0; j < 4; ++j)
#pragma unroll
            for (int r = 0; r < 4; ++r)
                Cb[(size_t)(i * 16 + orow + r) * ldc + j * 16 + fr] = f2bf(acc[i][j][r]);
}

// ---- Z GEMM: Z[M x 6144] = xg[M x 2048] @ [S_a|S_b|S_c], slices 3p..3p+2 ----
__global__ __launch_bounds__(256) void k_gemmZ(const u16* __restrict__ Xg,
                                               const u16* __restrict__ ST,
                                               u16* __restrict__ Z, int pass) {
    __shared__ u16 Asl[128 * 32];
    __shared__ u16 Bsl[128 * 32];
    const int tid = threadIdx.x;
    const int wave = tid >> 6, lane = tid & 63;
    const int m0 = blockIdx.x * 128;
    const int sl = blockIdx.y >> 4;          // slice within pass (0..2)
    const int nIn = (blockIdx.y & 15) * 128;
    const int slice = pass * 3 + sl;
    const u16* Ab = Xg + (size_t)m0 * 2048;
    const u16* Bb = ST + (size_t)slice * SSTR + (size_t)nIn * NNODE;
    const int tr = tid >> 2;
    const int tc = (tid & 3) * 8;
    char* AslB = (char*)Asl + wave * 1024;
    char* BslB = (char*)Bsl + wave * 1024;
    const int wm = (wave & 1) * 64, wn = (wave >> 1) * 64;
    const int fr = lane & 15;
    const int fk = (lane >> 4) * 8;
    f32x4 acc[4][4];
#pragma unroll
    for (int i = 0; i < 4; ++i)
#pragma unroll
        for (int j = 0; j < 4; ++j) acc[i][j] = (f32x4){0.f, 0.f, 0.f, 0.f};

    for (int k0 = 0; k0 < 2048; k0 += 32) {
        gld16(Ab + (size_t)tr * 2048 + k0 + tc, AslB);
        gld16(Ab + (size_t)(tr + 64) * 2048 + k0 + tc, AslB + 4096);
        gld16(Bb + (size_t)tr * NNODE + k0 + tc, BslB);
        gld16(Bb + (size_t)(tr + 64) * NNODE + k0 + tc, BslB + 4096);
        __syncthreads();
        bf16x8 af[4], bf[4];
#pragma unroll
        for (int i = 0; i < 4; ++i)
            af[i] = *(const bf16x8*)&Asl[(wm + i * 16 + fr) * 32 + fk];
#pragma unroll
        for (int j = 0; j < 4; ++j)
            bf[j] = *(const bf16x8*)&Bsl[(wn + j * 16 + fr) * 32 + fk];
#pragma unroll
        for (int i = 0; i < 4; ++i)
#pragma unroll
            for (int j = 0; j < 4; ++j)
                acc[i][j] = __builtin_amdgcn_mfma_f32_16x16x32_bf16(af[i], bf[j], acc[i][j], 0, 0, 0);
        __syncthreads();
    }
    u16* Cb = Z + (size_t)(m0 + wm) * 6144 + sl * 2048 + nIn + wn;
    const int orow = (lane >> 4) * 4;
#pragma unroll
    for (int i = 0; i < 4; ++i)
#pragma unroll
        for (int j = 0; j < 4; ++j)
#pragma unroll
            for (int r = 0; r < 4; ++r)
                Cb[(size_t)(i * 16 + orow + r) * 6144 + j * 16 + fr] = f2bf(acc[i][j][r]);
}

// ---------------- start conv: pad t by 1, 2 -> 32 channels (bf16 out) ----------------
__global__ __launch_bounds__(256) void k_start(const float* __restrict__ xin,
                                               const float* __restrict__ sw,
                                               const float* __restrict__ sb,
                                               u16* __restrict__ out, int b0) {
    int n = blockIdx.x * 256 + threadIdx.x;
    int t = blockIdx.y;
    int bl = blockIdx.z;
    int b = b0 + bl;
    float x0 = 0.f, x1 = 0.f;
    if (t > 0) {
        x0 = xin[((size_t)(b * 2 + 0) * NNODE + n) * 12 + (t - 1)];
        x1 = xin[((size_t)(b * 2 + 1) * NNODE + n) * 12 + (t - 1)];
    }
#pragma unroll
    for (int co = 0; co < 32; ++co) {
        float v = sw[co * 2 + 0] * x0 + sw[co * 2 + 1] * x1 + sb[co];
        out[((size_t)(bl * 32 + co) * 13 + t) * NNODE + n] = f2bf(v);
    }
}

// ------- dilated filter/gate conv (dot2) + tanh*sigmoid -> bf16 xg;
//         nxt init = gcn_bias + W0*xg (dot2); t==Tn-1 blocks also compute the
//         256-ch skip projection (dot2) into f32 skip. Pair-n per thread. -------
__global__ __launch_bounds__(256) void k_gate(const u16* __restrict__ cur,
                                              u16* __restrict__ xg,
                                              u16* __restrict__ nxt,
                                              float* __restrict__ skip,
                                              int T, int Tn, int d, int tbase,
                                              const float* __restrict__ fw,
                                              const float* __restrict__ fb,
                                              const float* __restrict__ gw,
                                              const float* __restrict__ gb,
                                              const float* __restrict__ gcwl,
                                              const float* __restrict__ gcbl,
                                              const float* __restrict__ skw,
                                              const float* __restrict__ skb,
                                              int b0, int donxt, int skinit) {
    __shared__ u32 wpf[1024];      // {fw0,fw1} bf16 pairs [ci*32+co]
    __shared__ u32 wpg[1024];      // {gw0,gw1}
    __shared__ u32 w0p[512];       // identity W ci-pairs [cip*32+co]
    __shared__ u32 wskp[4096];     // skip W [co*16+cip]
    int tid = threadIdx.x;
#pragma unroll
    for (int u0 = 0; u0 < 4; ++u0) {
        int u = tid + u0 * 256;
        int ci = u >> 5, co = u & 31;
        wpf[u] = pack2(fw[co * 64 + ci * 2], fw[co * 64 + ci * 2 + 1]);
        wpg[u] = pack2(gw[co * 64 + ci * 2], gw[co * 64 + ci * 2 + 1]);
    }
#pragma unroll
    for (int u0 = 0; u0 < 2; ++u0) {
        int u = tid + u0 * 256;
        int cip = u >> 5, co = u & 31;
        w0p[u] = pack2(gcwl[co * 224 + 2 * cip], gcwl[co * 224 + 2 * cip + 1]);
    }
#pragma unroll
    for (int u0 = 0; u0 < 16; ++u0) {
        int u = tid + u0 * 256;
        int co = u >> 4, cip = u & 15;
        wskp[u] = pack2(skw[co * 32 + 2 * cip], skw[co * 32 + 2 * cip + 1]);
    }
    __syncthreads();
    int n = blockIdx.x * 512 + tid * 2;  // n, n+1
    int t = blockIdx.y + tbase;
    int bl = blockIdx.z;
    float f0[32], f1[32], g0[32], g1[32];
#pragma unroll
    for (int co = 0; co < 32; ++co) { f0[co] = 0.f; f1[co] = 0.f; g0[co] = 0.f; g1[co] = 0.f; }
    for (int ci = 0; ci < 32; ++ci) {
        size_t ba = ((size_t)(bl * 32 + ci) * T + t) * NNODE + n;
        size_t bb = ((size_t)(bl * 32 + ci) * T + t + d) * NNODE + n;
        u32 ua = *(const u32*)&cur[ba];
        u32 ub = *(const u32*)&cur[bb];
        u32 p0 = (ua & 0xffffu) | (ub << 16);       // {xa(n), xb(n)}
        u32 p1 = (ua >> 16) | (ub & 0xffff0000u);   // {xa(n+1), xb(n+1)}
#pragma unroll
        for (int cq = 0; cq < 8; ++cq) {
            uint4 wf = *(const uint4*)&wpf[ci * 32 + cq * 4];
            uint4 wg = *(const uint4*)&wpg[ci * 32 + cq * 4];
            f0[cq * 4 + 0] = dot2bf(wf.x, p0, f0[cq * 4 + 0]);
            f1[cq * 4 + 0] = dot2bf(wf.x, p1, f1[cq * 4 + 0]);
            f0[cq * 4 + 1] = dot2bf(wf.y, p0, f0[cq * 4 + 1]);
            f1[cq * 4 + 1] = dot2bf(wf.y, p1, f1[cq * 4 + 1]);
            f0[cq * 4 + 2] = dot2bf(wf.z, p0, f0[cq * 4 + 2]);
            f1[cq * 4 + 2] = dot2bf(wf.z, p1, f1[cq * 4 + 2]);
            f0[cq * 4 + 3] = dot2bf(wf.w, p0, f0[cq * 4 + 3]);
            f1[cq * 4 + 3] = dot2bf(wf.w, p1, f1[cq * 4 + 3]);
            g0[cq * 4 + 0] = dot2bf(wg.x, p0, g0[cq * 4 + 0]);
            g1[cq * 4 + 0] = dot2bf(wg.x, p1, g1[cq * 4 + 0]);
            g0[cq * 4 + 1] = dot2bf(wg.y, p0, g0[cq * 4 + 1]);
            g1[cq * 4 + 1] = dot2bf(wg.y, p1, g1[cq * 4 + 1]);
            g0[cq * 4 + 2] = dot2bf(wg.z, p0, g0[cq * 4 + 2]);
            g1[cq * 4 + 2] = dot2bf(wg.z, p1, g1[cq * 4 + 2]);
            g0[cq * 4 + 3] = dot2bf(wg.w, p0, g0[cq * 4 + 3]);
            g1[cq * 4 + 3] = dot2bf(wg.w, p1, g1[cq * 4 + 3]);
        }
    }
#pragma unroll
    for (int co = 0; co < 32; ++co) {
        float fbv = fb[co], gbv = gb[co];
        float a0 = tanhf(f0[co] + fbv) * (1.f / (1.f + expf(-(g0[co] + gbv))));
        float a1 = tanhf(f1[co] + fbv) * (1.f / (1.f + expf(-(g1[co] + gbv))));
        f0[co] = a0; f1[co] = a1;  // keep for identity/skip mixes
        if (donxt) {
            size_t o = ((size_t)(bl * 32 + co) * Tn + t) * NNODE + n;
            *(u32*)&xg[o] = pack2(a0, a1);
        }
    }
    // packed activation pairs for the dot2 mixes
    u32 fp0[16], fp1[16];
#pragma unroll
    for (int cip = 0; cip < 16; ++cip) {
        fp0[cip] = pack2(f0[2 * cip], f0[2 * cip + 1]);
        fp1[cip] = pack2(f1[2 * cip], f1[2 * cip + 1]);
    }
    if (donxt) {
#pragma unroll
        for (int cop = 0; cop < 32; ++cop) {
            float s0 = gcbl[cop], s1 = s0;
#pragma unroll
            for (int c4 = 0; c4 < 4; ++c4) {
                uint4 w = *(const uint4*)&w0p[(c4 * 4) * 32 + cop];
                // note: w0p is [cip][co] with stride 32 -> gather 4 cips
                s0 = dot2bf(w0p[(c4 * 4 + 0) * 32 + cop], fp0[c4 * 4 + 0], s0);
                s1 = dot2bf(w0p[(c4 * 4 + 0) * 32 + cop], fp1[c4 * 4 + 0], s1);
                s0 = dot2bf(w0p[(c4 * 4 + 1) * 32 + cop], fp0[c4 * 4 + 1], s0);
                s1 = dot2bf(w0p[(c4 * 4 + 1) * 32 + cop], fp1[c4 * 4 + 1], s1);
                s0 = dot2bf(w0p[(c4 * 4 + 2) * 32 + cop], fp0[c4 * 4 + 2], s0);
                s1 = dot2bf(w0p[(c4 * 4 + 2) * 32 + cop], fp1[c4 * 4 + 2], s1);
                s0 = dot2bf(w0p[(c4 * 4 + 3) * 32 + cop], fp0[c4 * 4 + 3], s0);
                s1 = dot2bf(w0p[(c4 * 4 + 3) * 32 + cop], fp1[c4 * 4 + 3], s1);
                (void)w;
            }
            size_t o = ((size_t)(bl * 32 + cop) * Tn + t) * NNODE + n;
            *(u32*)&nxt[o] = pack2(s0, s1);
        }
    }
    if (t == Tn - 1) {
        int b = b0 + bl;
        for (int cop = 0; cop < 256; ++cop) {
            float a0 = 0.f, a1 = 0.f;
#pragma unroll
            for (int c4 = 0; c4 < 4; ++c4) {
                uint4 w = *(const uint4*)&wskp[cop * 16 + c4 * 4];
                a0 = dot2bf(w.x, fp0[c4 * 4 + 0], a0);
                a1 = dot2bf(w.x, fp1[c4 * 4 + 0], a1);
                a0 = dot2bf(w.y, fp0[c4 * 4 + 1], a0);
                a1 = dot2bf(w.y, fp1[c4 * 4 + 1], a1);
                a0 = dot2bf(w.z, fp0[c4 * 4 + 2], a0);
                a1 = dot2bf(w.z, fp1[c4 * 4 + 2], a1);
                a0 = dot2bf(w.w, fp0[c4 * 4 + 3], a0);
                a1 = dot2bf(w.w, fp1[c4 * 4 + 3], a1);
            }
            size_t o = ((size_t)(b * 256) + cop) * NNODE + n;
            float bs = skb[cop];
            if (skinit) {
                *(float2*)&skip[o] = make_float2(a0 + bs, a1 + bs);
            } else {
                float2 old = *(const float2*)&skip[o];
                *(float2*)&skip[o] = make_float2(old.x + a0 + bs, old.y + a1 + bs);
            }
        }
    }
}

// ---- GCN mix+accumulate (dot2): nxt(bf16) += sum_g Wg*Z[:,g*2048..]; pass1 +resid+BN ----
__global__ __launch_bounds__(256) void k_accum(const u16* __restrict__ Z,
                                               int cbase,
                                               const float* __restrict__ gcnw,
                                               u16* __restrict__ outp,
                                               const u16* __restrict__ resid,
                                               int Tn, int d, int finalf,
                                               const float* __restrict__ bng,
                                               const float* __restrict__ bnb,
                                               const float* __restrict__ bnm,
                                               const float* __restrict__ bnv) {
    __shared__ u32 wp3[3][16][32];  // [g][cip][co], bf16 pairs over ci
    int tid = threadIdx.x;
    for (int u = tid; u < 1536; u += 256) {
        int g = u >> 9, cip = (u >> 5) & 15, co = u & 31;
        wp3[g][cip][co] = pack2(gcnw[co * 224 + cbase + g * 32 + 2 * cip],
                                gcnw[co * 224 + cbase + g * 32 + 2 * cip + 1]);
    }
    __syncthreads();
    int n = blockIdx.x * 512 + tid * 2;  // n, n+1
    int t = blockIdx.y, bl = blockIdx.z;
    float a0[32], a1[32];
#pragma unroll
    for (int co = 0; co < 32; ++co) { a0[co] = 0.f; a1[co] = 0.f; }
    for (int cip = 0; cip < 16; ++cip) {
        size_t m0r = (size_t)(bl * 32 + 2 * cip) * Tn + t;
        size_t m1r = m0r + Tn;
#pragma unroll
        for (int g = 0; g < 3; ++g) {
            u32 z0 = *(const u32*)&Z[m0r * 6144 + g * 2048 + n];
            u32 z1 = *(const u32*)&Z[m1r * 6144 + g * 2048 + n];
            u32 pk0 = (z0 & 0xffffu) | (z1 << 16);      // {Z_2cip(n), Z_2cip+1(n)}
            u32 pk1 = (z0 >> 16) | (z1 & 0xffff0000u);  // same for n+1
#pragma unroll
            for (int cq = 0; cq < 8; ++cq) {
                uint4 w = *(const uint4*)&wp3[g][cip][cq * 4];
                a0[cq * 4 + 0] = dot2bf(w.x, pk0, a0[cq * 4 + 0]);
                a1[cq * 4 + 0] = dot2bf(w.x, pk1, a1[cq * 4 + 0]);
                a0[cq * 4 + 1] = dot2bf(w.y, pk0, a0[cq * 4 + 1]);
                a1[cq * 4 + 1] = dot2bf(w.y, pk1, a1[cq * 4 + 1]);
                a0[cq * 4 + 2] = dot2bf(w.z, pk0, a0[cq * 4 + 2]);
                a1[cq * 4 + 2] = dot2bf(w.z, pk1, a1[cq * 4 + 2]);
                a0[cq * 4 + 3] = dot2bf(w.w, pk0, a0[cq * 4 + 3]);
                a1[cq * 4 + 3] = dot2bf(w.w, pk1, a1[cq * 4 + 3]);
            }
        }
    }
#pragma unroll
    for (int co = 0; co < 32; ++co) {
        size_t o = ((size_t)(bl * 32 + co) * Tn + t) * NNODE + n;
        u32 oo = *(const u32*)&outp[o];
        float v0 = bflo(oo) + a0[co];
        float v1 = bfhi(oo) + a1[co];
        if (finalf) {
            size_t ro = ((size_t)(bl * 32 + co) * (Tn + d) + t + d) * NNODE + n;
            u32 rr = *(const u32*)&resid[ro];
            v0 += bflo(rr); v1 += bfhi(rr);
            float inv = bng[co] * rsqrtf(bnv[co] + 1e-5f);
            float mu = bnm[co], be = bnb[co];
            v0 = (v0 - mu) * inv + be;
            v1 = (v1 - mu) * inv + be;
        }
        *(u32*)&outp[o] = pack2(v0, v1);
    }
}

// ---- end head prep: skipT[b][n][sc] = bf16(relu(skip[b][sc][n])) ----
__global__ __launch_bounds__(256) void k_skipT(const float* __restrict__ skip,
                                               u16* __restrict__ skipT) {
    __shared__ float tile[32][33];
    int b = blockIdx.z;
    int n0 = blockIdx.x * 32, c0 = blockIdx.y * 32;
    int tx = threadIdx.x & 31, ty = threadIdx.x >> 5;
#pragma unroll
    for (int p = 0; p < 4; ++p)
        tile[ty + p * 8][tx] = skip[((size_t)b * 256 + c0 + ty + p * 8) * NNODE + n0 + tx];
    __syncthreads();
#pragma unroll
    for (int p = 0; p < 4; ++p)
        skipT[((size_t)b * NNODE + n0 + ty + p * 8) * 256 + c0 + tx] =
            f2bf(fmaxf(tile[tx][ty + p * 8], 0.f));
}

__global__ __launch_bounds__(256) void k_cast(const float* __restrict__ src,
                                              u16* __restrict__ dst) {
    int i = blockIdx.x * 256 + threadIdx.x;
    dst[i] = f2bf(src[i]);
}

// ---- end1 MFMA: h[b][e][n] = relu(E1[e,:] . relu(skip)[b,:,n] + b1[e]) ----
__global__ __launch_bounds__(256) void k_end1m(const u16* __restrict__ E1,
                                               const u16* __restrict__ skT,
                                               const float* __restrict__ bias,
                                               u16* __restrict__ h) {
    __shared__ u16 Asl[128 * 32];
    __shared__ u16 Bsl[128 * 32];
    const int tid = threadIdx.x;
    const int wave = tid >> 6, lane = tid & 63;
    const int b = blockIdx.z;
    const int m0 = blockIdx.y * 128;
    const int n0 = blockIdx.x * 128;
    const int tr = tid >> 2;
    const int tc = (tid & 3) * 8;
    char* AslB = (char*)Asl + wave * 1024;
    char* BslB = (char*)Bsl + wave * 1024;
    const int wm = (wave & 1) * 64, wn = (wave >> 1) * 64;
    const int fr = lane & 15;
    const int fk = (lane >> 4) * 8;
    const u16* Ab = E1 + (size_t)m0 * 256;
    const u16* Bb = skT + ((size_t)b * NNODE + n0) * 256;
    f32x4 acc[4][4];
#pragma unroll
    for (int i = 0; i < 4; ++i)
#pragma unroll
        for (int j = 0; j < 4; ++j) acc[i][j] = (f32x4){0.f, 0.f, 0.f, 0.f};
    for (int k0 = 0; k0 < 256; k0 += 32) {
        gld16(Ab + (size_t)tr * 256 + k0 + tc, AslB);
        gld16(Ab + (size_t)(tr + 64) * 256 + k0 + tc, AslB + 4096);
        gld16(Bb + (size_t)tr * 256 + k0 + tc, BslB);
        gld16(Bb + (size_t)(tr + 64) * 256 + k0 + tc, BslB + 4096);
        __syncthreads();
        bf16x8 af[4], bf[4];
#pragma unroll
        for (int i = 0; i < 4; ++i)
            af[i] = *(const bf16x8*)&Asl[(wm + i * 16 + fr) * 32 + fk];
#pragma unroll
        for (int j = 0; j < 4; ++j)
            bf[j] = *(const bf16x8*)&Bsl[(wn + j * 16 + fr) * 32 + fk];
#pragma unroll
        for (int i = 0; i < 4; ++i)
#pragma unroll
            for (int j = 0; j < 4; ++j)
                acc[i][j] = __builtin_amdgcn_mfma_f32_16x16x32_bf16(af[i], bf[j], acc[i][j], 0, 0, 0);
        __syncthreads();
    }
    const int orow = (lane >> 4) * 4;
#pragma unroll
    for (int i = 0; i < 4; ++i)
#pragma unroll
        for (int r = 0; r < 4; ++r) {
            int m = m0 + wm + i * 16 + orow + r;  // e index, < 512
            float bs = bias[m];
            size_t ob = ((size_t)b * 512 + m) * NNODE + n0 + wn;
#pragma unroll
            for (int j = 0; j < 4; ++j)
                h[ob + j * 16 + fr] = f2bf(fmaxf(acc[i][j][r] + bs, 0.f));
        }
}

// ---- end2: all 12 outputs per block; h read exactly once ----
__global__ __launch_bounds__(256) void k_end2(const u16* __restrict__ h,
                                              const float* __restrict__ w,
                                              const float* __restrict__ bias,
                                              float* __restrict__ out) {
    __shared__ float wl[12][512];  // 24 KB
    int tid = threadIdx.x;
    for (int u = tid; u < 6144; u += 256) wl[u >> 9][u & 511] = w[u];
    __syncthreads();
    int n = blockIdx.x * 256 + tid;
    int b = blockIdx.y;
    float acc[12];
#pragma unroll
    for (int o = 0; o < 12; ++o) acc[o] = 0.f;
#pragma unroll 4
    for (int e = 0; e < 512; ++e) {
        float v = bf2f(h[((size_t)(b * 512) + e) * NNODE + n]);
#pragma unroll
        for (int o = 0; o < 12; ++o) acc[o] += wl[o][e] * v;
    }
#pragma unroll
    for (int o = 0; o < 12; ++o)
        out[((size_t)(b * 12) + o) * NNODE + n] = acc[o] + bias[o];
}

extern "C" void kernel_launch(void* const* d_in, const int* in_sizes, int n_in,
                              void* d_out, int out_size, void* d_ws, size_t ws_size,
                              hipStream_t stream) {
    const float* x_in = (const float*)d_in[0];
    const float* A    = (const float*)d_in[1];
    const float* nv1  = (const float*)d_in[2];
    const float* nv2  = (const float*)d_in[3];
    const float* fw   = (const float*)d_in[4];
    const float* fb   = (const float*)d_in[5];
    const float* gw   = (const float*)d_in[6];
    const float* gb   = (const float*)d_in[7];
    const float* skw  = (const float*)d_in[8];
    const float* skb  = (const float*)d_in[9];
    const float* gcw  = (const float*)d_in[10];
    const float* gcb  = (const float*)d_in[11];
    const float* bng  = (const float*)d_in[12];
    const float* bnb  = (const float*)d_in[13];
    const float* bnm  = (const float*)d_in[14];
    const float* bnv  = (const float*)d_in[15];
    const float* stw  = (const float*)d_in[16];
    const float* stb  = (const float*)d_in[17];
    const float* e1w  = (const float*)d_in[18];
    const float* e1b  = (const float*)d_in[19];
    const float* e2w  = (const float*)d_in[20];
    const float* e2b  = (const float*)d_in[21];
    (void)in_sizes; (void)n_in; (void)out_size;

    // BL=16 (one chunk) needs 239,075,328 B; BL=8 fallback 161,480,704 B.
    const int BL = (ws_size >= 239075328UL) ? 16 : 8;
    const int nch = 16 / BL;
    const size_t bufsz = (size_t)BL * 1703936UL;  // BL*32*13*2048*2

    char* base = (char*)d_ws;
    u16*   ST   = (u16*)base;
    float* skip = (float*)(base + 50331648UL);
    u16*   bufA = (u16*)(base + 83886080UL);
    u16*   bufB = (u16*)(base + 83886080UL + bufsz);
    u16*   xg   = (u16*)(base + 83886080UL + 2 * bufsz);
    u16*   Z    = (u16*)(base + 83886080UL + 2 * bufsz + (size_t)BL * 1572864UL);
    // startup overlays
    float* adp  = (float*)Z;
    u16*   Sbf  = (u16*)bufA;   // spans bufA(+bufB for BL=8)
    // post-loop overlays
    u16*   h     = (u16*)(base + 83886080UL);              // 33.5 MB
    u16*   skipT = (u16*)(base + 83886080UL + 33554432UL); // 16.8 MB
    u16*   E1bf  = (u16*)ST;

    k_adp_mm<<<dim3(8, 2048), 256, 0, stream>>>(nv1, nv2, adp);
    k_softmax<<<2048, 256, 0, stream>>>(adp);
    k_transp<<<dim3(64, 64, 3), 256, 0, stream>>>(A, adp, ST, Sbf);
    // (S_s^2)^T: A = S^T (even slices), BT = S (Sbf) -> odd slices
    k_gemm_mfma<<<dim3(16, 16, 3), 256, 0, stream>>>(
        ST, NNODE, 2 * SSTR, Sbf, SSTR, ST + SSTR, NNODE, 2 * SSTR, 0);

    static const int DIL[NLAYER] = {1, 2, 1, 2, 1, 2, 1, 2};
    for (int ch = 0; ch < nch; ++ch) {
        int b0 = ch * BL;
        k_start<<<dim3(8, 13, BL), 256, 0, stream>>>(x_in, stw, stb, bufA, b0);
        u16* cur = bufA;
        u16* nxt = bufB;
        int T = 13;
        for (int i = 0; i < NLAYER; ++i) {
            int d = DIL[i], Tn = T - d;
            int last = (i == NLAYER - 1);
            if (last) {
                // only the skip contribution survives: launch t = Tn-1 only
                k_gate<<<dim3(4, 1, BL), 256, 0, stream>>>(cur, xg, nxt, skip,
                    T, Tn, d, Tn - 1,
                    fw + i * 2048, fb + i * 32, gw + i * 2048, gb + i * 32,
                    gcw + i * 32 * 224, gcb + i * 32,
                    skw + i * 256 * 32, skb + i * 256, b0, 0, 0);
                break;
            }
            k_gate<<<dim3(4, Tn, BL), 256, 0, stream>>>(cur, xg, nxt, skip,
                T, Tn, d, 0,
                fw + i * 2048, fb + i * 32, gw + i * 2048, gb + i * 32,
                gcw + i * 32 * 224, gcb + i * 32,
                skw + i * 256 * 32, skb + i * 256, b0, 1, (i == 0) ? 1 : 0);
            int MB = BL * Tn / 4;  // M/128, M = BL*32*Tn
            const float* gcwi = gcw + i * 32 * 224;
            for (int p = 0; p < 2; ++p) {
                k_gemmZ<<<dim3(MB, 48), 256, 0, stream>>>(xg, ST, Z, p);
                k_accum<<<dim3(4, Tn, BL), 256, 0, stream>>>(
                    Z, 32 + 96 * p, gcwi, nxt, cur, Tn, d, p,
                    bng + i * 32, bnb + i * 32, bnm + i * 32, bnv + i * 32);
            }
            u16* tmp = cur; cur = nxt; nxt = tmp;
            T = Tn;
        }
    }
    k_cast<<<512, 256, 0, stream>>>(e1w, E1bf);
    k_skipT<<<dim3(64, 8, 16), 256, 0, stream>>>(skip, skipT);
    k_end1m<<<dim3(16, 4, 16), 256, 0, stream>>>(E1bf, skipT, e1b, h);
    k_end2<<<dim3(8, 16), 256, 0, stream>>>(h, e2w, e2b, (float*)d_out);
}

// Round 9
// 3185.007 us; speedup vs baseline: 1.1137x; 1.1137x over previous
//
#include <hip/hip_runtime.h>
#include <math.h>

// GraphWaveNet forward — Round 9: round-6 base (best, 3360us) + BK=64
// dual-subtile k_gemmZ (halves barrier count per MFMA; 32KB LDS) + single-read
// k_end2. Gate/skip/accum reverted to round-6 vectorized-f32-weight versions
// (round 8's strided-LDS dot2 gate regressed).
//
// Z = xg @ [S_a|S_b|S_c] (N=6144), k_accum mixes (32x32 per group) into bf16
// nxt; pass 1 adds resid+BN. nxt pre-init by k_gate (gcn bias + W0*xg).
// ST slice order [S0,S0^2,S1,S1^2,S2,S2^2]^T; pass p slices 3p..3p+2,
// W cols 32+96p+32g. skip telescopes (last time step only). End head = MFMA.
//
// Workspace (BL=16 if ws >= 239,075,328 B else BL=8; ws>=256MiB proven r4):
//   ST    6 x 2048^2 bf16                      @0           50,331,648
//   skip  16x256x2048 f32                      @50,331,648  33,554,432
//   bufA  BL x 32 x 13 x 2048 bf16             @83,886,080  BL*1,703,936
//   bufB  same                                 (adjacent)
//   xg    BL x 32 x 12 x 2048 bf16             (adjacent)   BL*1,572,864
//   Z     (BL*32*12) x 6144 bf16               (adjacent)   BL*4,718,592
// Overlays: adp f32 @Z, Sbf bf16 @bufA (startup); h bf16 @bufA.., skipT
// @bufA+33.5MB, E1bf @ST (post-loop; skip f32 region untouched).

#define NNODE 2048
#define NLAYER 8
#define SSTR ((size_t)NNODE * NNODE)

typedef unsigned short u16;
typedef unsigned int u32;
typedef __attribute__((ext_vector_type(8))) short bf16x8;
typedef __attribute__((ext_vector_type(4))) float f32x4;

__device__ __forceinline__ u16 f2bf(float f) {
    unsigned u = __builtin_bit_cast(unsigned, f);
    u += 0x7fffu + ((u >> 16) & 1u);   // round-to-nearest-even
    return (u16)(u >> 16);
}
__device__ __forceinline__ float bf2f(u16 h) {
    unsigned u = ((unsigned)h) << 16;
    return __builtin_bit_cast(float, u);
}
__device__ __forceinline__ float bflo(u32 p) { return __builtin_bit_cast(float, p << 16); }
__device__ __forceinline__ float bfhi(u32 p) { return __builtin_bit_cast(float, p & 0xffff0000u); }
__device__ __forceinline__ u32 pack2(float a, float b) {
    return (u32)f2bf(a) | ((u32)f2bf(b) << 16);
}

__device__ __forceinline__ void gld16(const void* g, void* l) {
    __builtin_amdgcn_global_load_lds(
        (const __attribute__((address_space(1))) unsigned int*)g,
        (__attribute__((address_space(3))) unsigned int*)l, 16, 0, 0);
}

// ---------------- adp = softmax(relu(nv1 @ nv2), axis=1) ----------------
__global__ __launch_bounds__(256) void k_adp_mm(const float* __restrict__ nv1,
                                                const float* __restrict__ nv2,
                                                float* __restrict__ P) {
    int v = blockIdx.y;
    int w = blockIdx.x * 256 + threadIdx.x;
    float acc = 0.f;
#pragma unroll
    for (int k = 0; k < 10; ++k) acc += nv1[v * 10 + k] * nv2[k * NNODE + w];
    P[(size_t)v * NNODE + w] = acc;
}

__global__ __launch_bounds__(256) void k_softmax(float* __restrict__ P) {
    int v = blockIdx.x, tid = threadIdx.x;
    float* row = P + (size_t)v * NNODE;
    float m = 0.f;
    for (int w = tid; w < NNODE; w += 256) m = fmaxf(m, fmaxf(row[w], 0.f));
#pragma unroll
    for (int off = 32; off > 0; off >>= 1) m = fmaxf(m, __shfl_down(m, off));
    __shared__ float redm[4];
    __shared__ float reds[4];
    int wave = tid >> 6, lane = tid & 63;
    if (lane == 0) redm[wave] = m;
    __syncthreads();
    m = fmaxf(fmaxf(redm[0], redm[1]), fmaxf(redm[2], redm[3]));
    float s = 0.f;
    for (int w = tid; w < NNODE; w += 256) s += expf(fmaxf(row[w], 0.f) - m);
#pragma unroll
    for (int off = 32; off > 0; off >>= 1) s += __shfl_down(s, off);
    if (lane == 0) reds[wave] = s;
    __syncthreads();
    s = reds[0] + reds[1] + reds[2] + reds[3];
    float inv = 1.f / s;
    for (int w = tid; w < NNODE; w += 256) row[w] = expf(fmaxf(row[w], 0.f) - m) * inv;
}

// ---- supports: S_s^T bf16 -> ST slice 2s; straight-cast S bf16 -> Sbf ----
__global__ __launch_bounds__(256) void k_transp(const float* __restrict__ A,
                                                const float* __restrict__ adp,
                                                u16* __restrict__ ST,
                                                u16* __restrict__ Sbf) {
    __shared__ float tile[32][33];
    int s = blockIdx.z;
    const float* src = (s < 2) ? (A + (size_t)s * SSTR) : adp;
    int v0 = blockIdx.y * 32, w0 = blockIdx.x * 32;
    int tx = threadIdx.x & 31, ty = threadIdx.x >> 5;  // 32 x 8
    u16* dst2 = Sbf + (size_t)s * SSTR;
#pragma unroll
    for (int p = 0; p < 4; ++p) {
        float v = src[(size_t)(v0 + ty + p * 8) * NNODE + w0 + tx];
        tile[ty + p * 8][tx] = v;
        dst2[(size_t)(v0 + ty + p * 8) * NNODE + w0 + tx] = f2bf(v);
    }
    __syncthreads();
    u16* dst = ST + (size_t)(2 * s) * SSTR;
#pragma unroll
    for (int p = 0; p < 4; ++p)
        dst[(size_t)(w0 + ty + p * 8) * NNODE + v0 + tx] = f2bf(tile[tx][ty + p * 8]);
}

// ---- generic bf16 MFMA GEMM (startup S^2 only): C[m,n]=sum_k A[m,k]*BT[n,k] ----
__global__ __launch_bounds__(256) void k_gemm_mfma(
    const u16* __restrict__ A, int lda, size_t asstr,
    const u16* __restrict__ BT, size_t bsstr,
    u16* __restrict__ C, int ldc, size_t csstr, int sbase) {
    __shared__ u16 Asl[128 * 32];
    __shared__ u16 Bsl[128 * 32];
    const int tid = threadIdx.x;
    const int wave = tid >> 6, lane = tid & 63;
    const int sidx = sbase + blockIdx.z;
    const u16* Ab = A + sidx * asstr + (size_t)blockIdx.y * 128 * lda;
    const u16* Bb = BT + sidx * bsstr + (size_t)blockIdx.x * 128 * NNODE;
    const int tr = tid >> 2;
    const int tc = (tid & 3) * 8;
    char* AslB = (char*)Asl + wave * 1024;
    char* BslB = (char*)Bsl + wave * 1024;
    const int wm = (wave & 1) * 64, wn = (wave >> 1) * 64;
    const int fr = lane & 15;
    const int fk = (lane >> 4) * 8;
    f32x4 acc[4][4];
#pragma unroll
    for (int i = 0; i < 4; ++i)
#pragma unroll
        for (int j = 0; j < 4; ++j) acc[i][j] = (f32x4){0.f, 0.f, 0.f, 0.f};

    for (int k0 = 0; k0 < 2048; k0 += 32) {
        gld16(Ab + (size_t)tr * lda + k0 + tc, AslB);
        gld16(Ab + (size_t)(tr + 64) * lda + k0 + tc, AslB + 4096);
        gld16(Bb + (size_t)tr * NNODE + k0 + tc, BslB);
        gld16(Bb + (size_t)(tr + 64) * NNODE + k0 + tc, BslB + 4096);
        __syncthreads();
        bf16x8 af[4], bf[4];
#pragma unroll
        for (int i = 0; i < 4; ++i)
            af[i] = *(const bf16x8*)&Asl[(wm + i * 16 + fr) * 32 + fk];
#pragma unroll
        for (int j = 0; j < 4; ++j)
            bf[j] = *(const bf16x8*)&Bsl[(wn + j * 16 + fr) * 32 + fk];
#pragma unroll
        for (int i = 0; i < 4; ++i)
#pragma unroll
            for (int j = 0; j < 4; ++j)
                acc[i][j] = __builtin_amdgcn_mfma_f32_16x16x32_bf16(af[i], bf[j], acc[i][j], 0, 0, 0);
        __syncthreads();
    }
    u16* Cb = C + sidx * csstr + (size_t)(blockIdx.y * 128 + wm) * ldc + blockIdx.x * 128 + wn;
    const int orow = (lane >> 4) * 4;
#pragma unroll
    for (int i = 0; i < 4; ++i)
#pragma unroll
        for (int j = 0; j < 4; ++j)
#pragma unroll
            for (int r = 0; r < 4; ++r)
                Cb[(size_t)(i * 16 + orow + r) * ldc + j * 16 + fr] = f2bf(acc[i][j][r]);
}

// ---- Z GEMM: Z[M x 6144] = xg[M x 2048] @ [S_a|S_b|S_c], slices 3p..3p+2 ----
// BK=64 via two 32-col sub-tiles (same bank pattern as BK=32, contiguous
// global_load_lds destinations), halving barrier count per MFMA. LDS 32KB.
__global__ __launch_bounds__(256) void k_gemmZ(const u16* __restrict__ Xg,
                                               const u16* __restrict__ ST,
                                               u16* __restrict__ Z, int pass) {
    __shared__ u16 Asl[2][128 * 32];
    __shared__ u16 Bsl[2][128 * 32];
    const int tid = threadIdx.x;
    const int wave = tid >> 6, lane = tid & 63;
    const int m0 = blockIdx.y * 128;
    const int slice = pass * 3 + (blockIdx.x >> 4);
    const int nIn = (blockIdx.x & 15) * 128;
    const u16* Ab = Xg + (size_t)m0 * 2048;
    const u16* Bb = ST + (size_t)slice * SSTR + (size_t)nIn * NNODE;
    const int tr = tid >> 2;
    const int tc = (tid & 3) * 8;
    char* AslB0 = (char*)Asl[0] + wave * 1024;
    char* AslB1 = (char*)Asl[1] + wave * 1024;
    char* BslB0 = (char*)Bsl[0] + wave * 1024;
    char* BslB1 = (char*)Bsl[1] + wave * 1024;
    const int wm = (wave & 1) * 64, wn = (wave >> 1) * 64;
    const int fr = lane & 15;
    const int fk = (lane >> 4) * 8;
    f32x4 acc[4][4];
#pragma unroll
    for (int i = 0; i < 4; ++i)
#pragma unroll
        for (int j = 0; j < 4; ++j) acc[i][j] = (f32x4){0.f, 0.f, 0.f, 0.f};

    for (int k0 = 0; k0 < 2048; k0 += 64) {
        gld16(Ab + (size_t)tr * 2048 + k0 + tc, AslB0);
        gld16(Ab + (size_t)(tr + 64) * 2048 + k0 + tc, AslB0 + 4096);
        gld16(Ab + (size_t)tr * 2048 + k0 + 32 + tc, AslB1);
        gld16(Ab + (size_t)(tr + 64) * 2048 + k0 + 32 + tc, AslB1 + 4096);
        gld16(Bb + (size_t)tr * NNODE + k0 + tc, BslB0);
        gld16(Bb + (size_t)(tr + 64) * NNODE + k0 + tc, BslB0 + 4096);
        gld16(Bb + (size_t)tr * NNODE + k0 + 32 + tc, BslB1);
        gld16(Bb + (size_t)(tr + 64) * NNODE + k0 + 32 + tc, BslB1 + 4096);
        __syncthreads();
#pragma unroll
        for (int h = 0; h < 2; ++h) {
            bf16x8 af[4], bf[4];
#pragma unroll
            for (int i = 0; i < 4; ++i)
                af[i] = *(const bf16x8*)&Asl[h][(wm + i * 16 + fr) * 32 + fk];
#pragma unroll
            for (int j = 0; j < 4; ++j)
                bf[j] = *(const bf16x8*)&Bsl[h][(wn + j * 16 + fr) * 32 + fk];
#pragma unroll
            for (int i = 0; i < 4; ++i)
#pragma unroll
                for (int j = 0; j < 4; ++j)
                    acc[i][j] = __builtin_amdgcn_mfma_f32_16x16x32_bf16(af[i], bf[j], acc[i][j], 0, 0, 0);
        }
        __syncthreads();
    }
    u16* Cb = Z + (size_t)(m0 + wm) * 6144 + blockIdx.x * 128 + wn;
    const int orow = (lane >> 4) * 4;
#pragma unroll
    for (int i = 0; i < 4; ++i)
#pragma unroll
        for (int j = 0; j < 4; ++j)
#pragma unroll
            for (int r = 0; r < 4; ++r)
                Cb[(size_t)(i * 16 + orow + r) * 6144 + j * 16 + fr] = f2bf(acc[i][j][r]);
}

// ---------------- start conv: pad t by 1, 2 -> 32 channels (bf16 out) ----------------
__global__ __launch_bounds__(256) void k_start(const float* __restrict__ xin,
                                               const float* __restrict__ sw,
                                               const float* __restrict__ sb,
                                               u16* __restrict__ out, int b0) {
    int n = blockIdx.x * 256 + threadIdx.x;
    int t = blockIdx.y;
    int bl = blockIdx.z;
    int b = b0 + bl;
    float x0 = 0.f, x1 = 0.f;
    if (t > 0) {
        x0 = xin[((size_t)(b * 2 + 0) * NNODE + n) * 12 + (t - 1)];
        x1 = xin[((size_t)(b * 2 + 1) * NNODE + n) * 12 + (t - 1)];
    }
#pragma unroll
    for (int co = 0; co < 32; ++co) {
        float v = sw[co * 2 + 0] * x0 + sw[co * 2 + 1] * x1 + sb[co];
        out[((size_t)(bl * 32 + co) * 13 + t) * NNODE + n] = f2bf(v);
    }
}

// ------- dilated filter/gate conv + tanh*sigmoid -> bf16 xg; also writes
//         nxt init = gcn_bias + W0 * xg (identity group), bf16 -------
__global__ __launch_bounds__(256) void k_gate(const u16* __restrict__ cur,
                                              u16* __restrict__ xg,
                                              u16* __restrict__ nxt,
                                              int T, int Tn, int d,
                                              const float* __restrict__ fw,
                                              const float* __restrict__ fb,
                                              const float* __restrict__ gw,
                                              const float* __restrict__ gb,
                                              const float* __restrict__ gcwl,
                                              const float* __restrict__ gcbl,
                                              int donxt) {
    __shared__ float4 wp[1024];     // [ci*32+co] = {fw0, fw1, gw0, gw1}
    __shared__ float w0[32][33];    // identity-group W: [ci][co']
    int tid = threadIdx.x;
#pragma unroll
    for (int u = 0; u < 4; ++u) {
        int idx = tid + u * 256;
        int ci = idx >> 5, co = idx & 31;
        wp[idx] = make_float4(fw[co * 64 + ci * 2], fw[co * 64 + ci * 2 + 1],
                              gw[co * 64 + ci * 2], gw[co * 64 + ci * 2 + 1]);
        w0[ci][co] = gcwl[co * 224 + ci];
    }
    __syncthreads();
    int n = blockIdx.x * 512 + tid * 2;  // n, n+1
    int t = blockIdx.y;
    int bl = blockIdx.z;
    float f0[32], f1[32], g0[32], g1[32];
#pragma unroll
    for (int co = 0; co < 32; ++co) { f0[co] = 0.f; f1[co] = 0.f; g0[co] = 0.f; g1[co] = 0.f; }
    for (int ci = 0; ci < 32; ++ci) {
        size_t ba = ((size_t)(bl * 32 + ci) * T + t) * NNODE + n;
        size_t bb = ((size_t)(bl * 32 + ci) * T + t + d) * NNODE + n;
        u32 ua = *(const u32*)&cur[ba];
        u32 ub = *(const u32*)&cur[bb];
        float xa0 = bflo(ua), xa1 = bfhi(ua);
        float xb0 = bflo(ub), xb1 = bfhi(ub);
#pragma unroll
        for (int co = 0; co < 32; ++co) {
            float4 w = wp[ci * 32 + co];
            f0[co] += w.x * xa0 + w.y * xb0;
            f1[co] += w.x * xa1 + w.y * xb1;
            g0[co] += w.z * xa0 + w.w * xb0;
            g1[co] += w.z * xa1 + w.w * xb1;
        }
    }
#pragma unroll
    for (int co = 0; co < 32; ++co) {
        float fbv = fb[co], gbv = gb[co];
        float a0 = tanhf(f0[co] + fbv) * (1.f / (1.f + expf(-(g0[co] + gbv))));
        float a1 = tanhf(f1[co] + fbv) * (1.f / (1.f + expf(-(g1[co] + gbv))));
        f0[co] = a0; f1[co] = a1;  // keep for identity mix
        size_t o = ((size_t)(bl * 32 + co) * Tn + t) * NNODE + n;
        *(u32*)&xg[o] = pack2(a0, a1);
    }
    if (donxt) {
#pragma unroll
        for (int cop = 0; cop < 32; ++cop) {
            float s0 = gcbl[cop], s1 = s0;
#pragma unroll
            for (int ci = 0; ci < 32; ++ci) {
                float wv = w0[ci][cop];
                s0 += wv * f0[ci];
                s1 += wv * f1[ci];
            }
            size_t o = ((size_t)(bl * 32 + cop) * Tn + t) * NNODE + n;
            *(u32*)&nxt[o] = pack2(s0, s1);
        }
    }
}

// ---- skip conv, last time step only; accumulates across layers (f32) ----
__global__ __launch_bounds__(256) void k_skip(const u16* __restrict__ xg,
                                              float* __restrict__ skip, int Tn,
                                              const float* __restrict__ sw,
                                              const float* __restrict__ sb, int b0, int init) {
    __shared__ float wl[256];  // 8 sc rows x 32 ci
    int tid = threadIdx.x;
    int sc0 = blockIdx.y * 8;
    wl[tid] = sw[sc0 * 32 + tid];
    __syncthreads();
    int n = blockIdx.x * 512 + tid * 2;  // n, n+1
    int bl = blockIdx.z;
    float a0[8], a1[8];
#pragma unroll
    for (int j = 0; j < 8; ++j) { a0[j] = 0.f; a1[j] = 0.f; }
    for (int ci = 0; ci < 32; ci += 2) {
        u32 p0 = *(const u32*)&xg[((size_t)(bl * 32 + ci + 0) * Tn + (Tn - 1)) * NNODE + n];
        u32 p1 = *(const u32*)&xg[((size_t)(bl * 32 + ci + 1) * Tn + (Tn - 1)) * NNODE + n];
        float v00 = bflo(p0), v01 = bfhi(p0);
        float v10 = bflo(p1), v11 = bfhi(p1);
#pragma unroll
        for (int j = 0; j < 8; ++j) {
            float wA = wl[j * 32 + ci], wB = wl[j * 32 + ci + 1];
            a0[j] += wA * v00 + wB * v10;
            a1[j] += wA * v01 + wB * v11;
        }
    }
    int b = b0 + bl;
#pragma unroll
    for (int j = 0; j < 8; ++j) {
        size_t o = ((size_t)(b * 256) + sc0 + j) * NNODE + n;
        float bsv = sb[sc0 + j];
        if (init) {
            *(float2*)&skip[o] = make_float2(a0[j] + bsv, a1[j] + bsv);
        } else {
            float2 old = *(const float2*)&skip[o];
            *(float2*)&skip[o] = make_float2(old.x + a0[j] + bsv, old.y + a1[j] + bsv);
        }
    }
}

// ---- GCN mix+accumulate: nxt(bf16) += sum_g Wg * Z[:, g*2048..]; pass1 adds resid+BN ----
__global__ __launch_bounds__(256) void k_accum(const u16* __restrict__ Z,
                                               int cbase,
                                               const float* __restrict__ gcnw,
                                               u16* __restrict__ outp,
                                               const u16* __restrict__ resid,
                                               int Tn, int d, int finalf,
                                               const float* __restrict__ bng,
                                               const float* __restrict__ bnb,
                                               const float* __restrict__ bnm,
                                               const float* __restrict__ bnv) {
    __shared__ float wl[3][32][32];  // [g][ci][co]
    int tid = threadIdx.x;
    for (int u = tid; u < 3072; u += 256) {
        int g = u >> 10, ci = (u >> 5) & 31, co = u & 31;
        wl[g][ci][co] = gcnw[co * 224 + cbase + g * 32 + ci];
    }
    __syncthreads();
    int n = blockIdx.x * 512 + tid * 2;  // n, n+1
    int t = blockIdx.y, bl = blockIdx.z;
    float a0[32], a1[32];
#pragma unroll
    for (int co = 0; co < 32; ++co) { a0[co] = 0.f; a1[co] = 0.f; }
    for (int ci = 0; ci < 32; ++ci) {
        size_t m = (size_t)(bl * 32 + ci) * Tn + t;
#pragma unroll
        for (int g = 0; g < 3; ++g) {
            u32 zz = *(const u32*)&Z[m * 6144 + g * 2048 + n];
            float v0 = bflo(zz), v1 = bfhi(zz);
#pragma unroll
            for (int cq = 0; cq < 8; ++cq) {
                float4 w = *(const float4*)&wl[g][ci][cq * 4];
                a0[cq * 4 + 0] += w.x * v0; a1[cq * 4 + 0] += w.x * v1;
                a0[cq * 4 + 1] += w.y * v0; a1[cq * 4 + 1] += w.y * v1;
                a0[cq * 4 + 2] += w.z * v0; a1[cq * 4 + 2] += w.z * v1;
                a0[cq * 4 + 3] += w.w * v0; a1[cq * 4 + 3] += w.w * v1;
            }
        }
    }
#pragma unroll
    for (int co = 0; co < 32; ++co) {
        size_t o = ((size_t)(bl * 32 + co) * Tn + t) * NNODE + n;
        u32 oo = *(const u32*)&outp[o];
        float v0 = bflo(oo) + a0[co];
        float v1 = bfhi(oo) + a1[co];
        if (finalf) {
            size_t ro = ((size_t)(bl * 32 + co) * (Tn + d) + t + d) * NNODE + n;
            u32 rr = *(const u32*)&resid[ro];
            v0 += bflo(rr); v1 += bfhi(rr);
            float inv = bng[co] * rsqrtf(bnv[co] + 1e-5f);
            float mu = bnm[co], be = bnb[co];
            v0 = (v0 - mu) * inv + be;
            v1 = (v1 - mu) * inv + be;
        }
        *(u32*)&outp[o] = pack2(v0, v1);
    }
}

// ---- end head prep: skipT[b][n][sc] = bf16(relu(skip[b][sc][n])) ----
__global__ __launch_bounds__(256) void k_skipT(const float* __restrict__ skip,
                                               u16* __restrict__ skipT) {
    __shared__ float tile[32][33];
    int b = blockIdx.z;
    int n0 = blockIdx.x * 32, c0 = blockIdx.y * 32;
    int tx = threadIdx.x & 31, ty = threadIdx.x >> 5;
#pragma unroll
    for (int p = 0; p < 4; ++p)
        tile[ty + p * 8][tx] = skip[((size_t)b * 256 + c0 + ty + p * 8) * NNODE + n0 + tx];
    __syncthreads();
#pragma unroll
    for (int p = 0; p < 4; ++p)
        skipT[((size_t)b * NNODE + n0 + ty + p * 8) * 256 + c0 + tx] =
            f2bf(fmaxf(tile[tx][ty + p * 8], 0.f));
}

__global__ __launch_bounds__(256) void k_cast(const float* __restrict__ src,
                                              u16* __restrict__ dst) {
    int i = blockIdx.x * 256 + threadIdx.x;
    dst[i] = f2bf(src[i]);
}

// ---- end1 MFMA: h[b][e][n] = relu(E1[e,:] . relu(skip)[b,:,n] + b1[e]) ----
__global__ __launch_bounds__(256) void k_end1m(const u16* __restrict__ E1,
                                               const u16* __restrict__ skT,
                                               const float* __restrict__ bias,
                                               u16* __restrict__ h) {
    __shared__ u16 Asl[128 * 32];
    __shared__ u16 Bsl[128 * 32];
    const int tid = threadIdx.x;
    const int wave = tid >> 6, lane = tid & 63;
    const int b = blockIdx.z;
    const int m0 = blockIdx.y * 128;
    const int n0 = blockIdx.x * 128;
    const int tr = tid >> 2;
    const int tc = (tid & 3) * 8;
    char* AslB = (char*)Asl + wave * 1024;
    char* BslB = (char*)Bsl + wave * 1024;
    const int wm = (wave & 1) * 64, wn = (wave >> 1) * 64;
    const int fr = lane & 15;
    const int fk = (lane >> 4) * 8;
    const u16* Ab = E1 + (size_t)m0 * 256;
    const u16* Bb = skT + ((size_t)b * NNODE + n0) * 256;
    f32x4 acc[4][4];
#pragma unroll
    for (int i = 0; i < 4; ++i)
#pragma unroll
        for (int j = 0; j < 4; ++j) acc[i][j] = (f32x4){0.f, 0.f, 0.f, 0.f};
    for (int k0 = 0; k0 < 256; k0 += 32) {
        gld16(Ab + (size_t)tr * 256 + k0 + tc, AslB);
        gld16(Ab + (size_t)(tr + 64) * 256 + k0 + tc, AslB + 4096);
        gld16(Bb + (size_t)tr * 256 + k0 + tc, BslB);
        gld16(Bb + (size_t)(tr + 64) * 256 + k0 + tc, BslB + 4096);
        __syncthreads();
        bf16x8 af[4], bf[4];
#pragma unroll
        for (int i = 0; i < 4; ++i)
            af[i] = *(const bf16x8*)&Asl[(wm + i * 16 + fr) * 32 + fk];
#pragma unroll
        for (int j = 0; j < 4; ++j)
            bf[j] = *(const bf16x8*)&Bsl[(wn + j * 16 + fr) * 32 + fk];
#pragma unroll
        for (int i = 0; i < 4; ++i)
#pragma unroll
            for (int j = 0; j < 4; ++j)
                acc[i][j] = __builtin_amdgcn_mfma_f32_16x16x32_bf16(af[i], bf[j], acc[i][j], 0, 0, 0);
        __syncthreads();
    }
    const int orow = (lane >> 4) * 4;
#pragma unroll
    for (int i = 0; i < 4; ++i)
#pragma unroll
        for (int r = 0; r < 4; ++r) {
            int m = m0 + wm + i * 16 + orow + r;  // e index, < 512
            float bs = bias[m];
            size_t ob = ((size_t)b * 512 + m) * NNODE + n0 + wn;
#pragma unroll
            for (int j = 0; j < 4; ++j)
                h[ob + j * 16 + fr] = f2bf(fmaxf(acc[i][j][r] + bs, 0.f));
        }
}

// ---- end2: all 12 outputs per block; h read exactly once ----
__global__ __launch_bounds__(256) void k_end2(const u16* __restrict__ h,
                                              const float* __restrict__ w,
                                              const float* __restrict__ bias,
                                              float* __restrict__ out) {
    __shared__ float wl[12][512];  // 24 KB
    int tid = threadIdx.x;
    for (int u = tid; u < 6144; u += 256) wl[u >> 9][u & 511] = w[u];
    __syncthreads();
    int n = blockIdx.x * 256 + tid;
    int b = blockIdx.y;
    float acc[12];
#pragma unroll
    for (int o = 0; o < 12; ++o) acc[o] = 0.f;
#pragma unroll 4
    for (int e = 0; e < 512; ++e) {
        float v = bf2f(h[((size_t)(b * 512) + e) * NNODE + n]);
#pragma unroll
        for (int o = 0; o < 12; ++o) acc[o] += wl[o][e] * v;
    }
#pragma unroll
    for (int o = 0; o < 12; ++o)
        out[((size_t)(b * 12) + o) * NNODE + n] = acc[o] + bias[o];
}

extern "C" void kernel_launch(void* const* d_in, const int* in_sizes, int n_in,
                              void* d_out, int out_size, void* d_ws, size_t ws_size,
                              hipStream_t stream) {
    const float* x_in = (const float*)d_in[0];
    const float* A    = (const float*)d_in[1];
    const float* nv1  = (const float*)d_in[2];
    const float* nv2  = (const float*)d_in[3];
    const float* fw   = (const float*)d_in[4];
    const float* fb   = (const float*)d_in[5];
    const float* gw   = (const float*)d_in[6];
    const float* gb   = (const float*)d_in[7];
    const float* skw  = (const float*)d_in[8];
    const float* skb  = (const float*)d_in[9];
    const float* gcw  = (const float*)d_in[10];
    const float* gcb  = (const float*)d_in[11];
    const float* bng  = (const float*)d_in[12];
    const float* bnb  = (const float*)d_in[13];
    const float* bnm  = (const float*)d_in[14];
    const float* bnv  = (const float*)d_in[15];
    const float* stw  = (const float*)d_in[16];
    const float* stb  = (const float*)d_in[17];
    const float* e1w  = (const float*)d_in[18];
    const float* e1b  = (const float*)d_in[19];
    const float* e2w  = (const float*)d_in[20];
    const float* e2b  = (const float*)d_in[21];
    (void)in_sizes; (void)n_in; (void)out_size;

    // BL=16 (one chunk) needs 239,075,328 B; BL=8 fallback 161,480,704 B.
    const int BL = (ws_size >= 239075328UL) ? 16 : 8;
    const int nch = 16 / BL;
    const size_t bufsz = (size_t)BL * 1703936UL;  // BL*32*13*2048*2

    char* base = (char*)d_ws;
    u16*   ST   = (u16*)base;
    float* skip = (float*)(base + 50331648UL);
    u16*   bufA = (u16*)(base + 83886080UL);
    u16*   bufB = (u16*)(base + 83886080UL + bufsz);
    u16*   xg   = (u16*)(base + 83886080UL + 2 * bufsz);
    u16*   Z    = (u16*)(base + 83886080UL + 2 * bufsz + (size_t)BL * 1572864UL);
    // startup overlays
    float* adp  = (float*)Z;
    u16*   Sbf  = (u16*)bufA;   // spans bufA(+bufB for BL=8)
    // post-loop overlays
    u16*   h     = (u16*)(base + 83886080UL);              // 33.5 MB
    u16*   skipT = (u16*)(base + 83886080UL + 33554432UL); // 16.8 MB
    u16*   E1bf  = (u16*)ST;

    k_adp_mm<<<dim3(8, 2048), 256, 0, stream>>>(nv1, nv2, adp);
    k_softmax<<<2048, 256, 0, stream>>>(adp);
    k_transp<<<dim3(64, 64, 3), 256, 0, stream>>>(A, adp, ST, Sbf);
    // (S_s^2)^T: A = S^T (even slices), BT = S (Sbf) -> odd slices
    k_gemm_mfma<<<dim3(16, 16, 3), 256, 0, stream>>>(
        ST, NNODE, 2 * SSTR, Sbf, SSTR, ST + SSTR, NNODE, 2 * SSTR, 0);

    static const int DIL[NLAYER] = {1, 2, 1, 2, 1, 2, 1, 2};
    for (int ch = 0; ch < nch; ++ch) {
        int b0 = ch * BL;
        k_start<<<dim3(8, 13, BL), 256, 0, stream>>>(x_in, stw, stb, bufA, b0);
        u16* cur = bufA;
        u16* nxt = bufB;
        int T = 13;
        for (int i = 0; i < NLAYER; ++i) {
            int d = DIL[i], Tn = T - d;
            int last = (i == NLAYER - 1);
            k_gate<<<dim3(4, Tn, BL), 256, 0, stream>>>(cur, xg, nxt, T, Tn, d,
                fw + i * 2048, fb + i * 32, gw + i * 2048, gb + i * 32,
                gcw + i * 32 * 224, gcb + i * 32, last ? 0 : 1);
            k_skip<<<dim3(4, 32, BL), 256, 0, stream>>>(xg, skip, Tn,
                skw + i * 256 * 32, skb + i * 256, b0, (i == 0) ? 1 : 0);
            if (last) break;  // layer 7's GCN output is dead
            int MB = BL * Tn / 4;  // M/128, M = BL*32*Tn
            const float* gcwi = gcw + i * 32 * 224;
            for (int p = 0; p < 2; ++p) {
                k_gemmZ<<<dim3(48, MB), 256, 0, stream>>>(xg, ST, Z, p);
                k_accum<<<dim3(4, Tn, BL), 256, 0, stream>>>(
                    Z, 32 + 96 * p, gcwi, nxt, cur, Tn, d, p,
                    bng + i * 32, bnb + i * 32, bnm + i * 32, bnv + i * 32);
            }
            u16* tmp = cur; cur = nxt; nxt = tmp;
            T = Tn;
        }
    }
    k_cast<<<512, 256, 0, stream>>>(e1w, E1bf);
    k_skipT<<<dim3(64, 8, 16), 256, 0, stream>>>(skip, skipT);
    k_end1m<<<dim3(16, 4, 16), 256, 0, stream>>>(E1bf, skipT, e1b, h);
    k_end2<<<dim3(8, 16), 256, 0, stream>>>(h, e2w, e2b, (float*)d_out);
}